// Round 1
// baseline (540.851 us; speedup 1.0000x reference)
//
#include <hip/hip_runtime.h>

// GlimpseNet on MI355X — fully fused single kernel.
// Shapes: B=128, C=3, H=W=512, P=16, NP=3, HG=256, HL=128, D_IN=2304, OUT=(128,384).
//
// R2 structure: ONE kernel, one block per batch row b (128 blocks x 512 threads).
//   phase 1: stage 3x64x64 zero-padded patch centered at coords into LDS (48 KiB).
//            Levels 16^2/32^2/64^2 are concentric sub-windows of the 64x64 patch
//            (dynamic_slice starts are in [0,512], never clamped; zero-padding is
//            center-consistent), so one staging serves all 3 foveation levels.
//   phase 2: glimpse row g[2304] in LDS:
//            level0 = center 16x16 (rows/cols 24..39)
//            level1 = 2x2 avg-pool of center 32x32 (rows/cols 16..47)
//            level2 = 4x4 avg-pool of full 64x64
//   phase 3: hs = relu(g @ w1 + b1): 2-way split-K over 512 threads, w1 columns
//            coalesced across lanes; w1 (2.36 MB) is L2-resident per XCD.
//            hl = relu(l @ w2 + b2) on threads 256..383.
//   phase 4: out[b][j] = relu(b3+b4 + hs@w3[:,j] + hl@w4[:,j]), one thread per j.
// No workspace, no inter-kernel sync, no partial round-trip.

#define B_    128
#define C_    3
#define H_    512
#define W_    512
#define HG    256
#define HL    128
#define DIN   2304
#define HOUT  384   // HG + HL
#define NT    512   // threads per block

__global__ __launch_bounds__(NT) void glimpse_fused(
    const float* __restrict__ x,  const float* __restrict__ l,
    const float* __restrict__ w1, const float* __restrict__ b1,
    const float* __restrict__ w2, const float* __restrict__ b2,
    const float* __restrict__ w3, const float* __restrict__ b3,
    const float* __restrict__ w4, const float* __restrict__ b4,
    float* __restrict__ out)
{
    __shared__ float ld[C_ * 64 * 64];   // 48 KiB staged patches [c][r][cc]
    __shared__ float g[DIN];             // 9 KiB glimpse row
    __shared__ float red[NT];            // split-K partials
    __shared__ float hs[HG];
    __shared__ float hl[HL];

    const int b = blockIdx.x;
    const int t = threadIdx.x;

    // coords: trunc(0.5*((l+1)*512)) — identical op order to the JAX reference.
    const float l0 = l[b * 2 + 0];
    const float l1 = l[b * 2 + 1];
    const int sx = (int)(((l0 + 1.0f) * 512.0f) * 0.5f);
    const int sy = (int)(((l1 + 1.0f) * 512.0f) * 0.5f);

    const float* xb = x + (size_t)b * (C_ * H_ * W_);

    // ---- phase 1: stage 3 channels of the 64x64 window, zero-padded ----
    for (int f = t; f < C_ * 4096; f += NT) {
        const int c  = f >> 12;
        const int r  = (f >> 6) & 63;
        const int cc = f & 63;
        const int ry = sy - 32 + r;
        const int rx = sx - 32 + cc;
        ld[f] = (ry >= 0 && ry < H_ && rx >= 0 && rx < W_)
                    ? xb[c * (H_ * W_) + ry * W_ + rx] : 0.0f;
    }
    __syncthreads();

    // ---- phase 2: glimpse g[(level*3+c)*256 + py*16+px] ----
    // idx blocks of 256 are wave-aligned -> level/c uniform per wave (no divergence).
    for (int idx = t; idx < DIN; idx += NT) {
        const int pos   = idx & 255;
        const int cl    = idx >> 8;        // level*3 + c
        const int level = cl / 3;
        const int c     = cl - level * 3;
        const int py    = pos >> 4;
        const int px    = pos & 15;
        const float* pc = ld + c * 4096;
        float v;
        if (level == 0) {
            v = pc[(24 + py) * 64 + 24 + px];
        } else if (level == 1) {
            float s = 0.0f;
            #pragma unroll
            for (int dy = 0; dy < 2; ++dy) {
                const float2 u = *(const float2*)&pc[(16 + 2 * py + dy) * 64 + 16 + 2 * px];
                s += u.x + u.y;
            }
            v = s * 0.25f;
        } else {
            float s = 0.0f;
            #pragma unroll
            for (int dy = 0; dy < 4; ++dy) {
                const float4 u = *(const float4*)&pc[(4 * py + dy) * 64 + 4 * px];
                s += (u.x + u.y) + (u.z + u.w);
            }
            v = s * 0.0625f;
        }
        g[idx] = v;
    }
    __syncthreads();

    // ---- phase 3: hs = relu(g @ w1 + b1), 2-way split-K (t>>8), 4 accs for ILP.
    // w1 is (2304,256) row-major: lanes j consecutive -> 256B coalesced per k.
    {
        const int j    = t & 255;
        const int half = t >> 8;                    // 0 or 1, uniform per wave
        const float* gp = g  + half * 1152;
        const float* wp = w1 + half * 1152 * HG + j;
        float a0 = 0.f, a1 = 0.f, a2 = 0.f, a3 = 0.f;
        #pragma unroll 2
        for (int k = 0; k < 1152; k += 4) {
            a0 += gp[k + 0] * wp[(k + 0) * HG];
            a1 += gp[k + 1] * wp[(k + 1) * HG];
            a2 += gp[k + 2] * wp[(k + 2) * HG];
            a3 += gp[k + 3] * wp[(k + 3) * HG];
        }
        red[t] = (a0 + a1) + (a2 + a3);
    }
    __syncthreads();

    if (t < HG) {
        hs[t] = fmaxf(red[t] + red[t + 256] + b1[t], 0.0f);
    } else if (t < HG + HL) {
        const int j = t - HG;
        hl[j] = fmaxf(l0 * w2[j] + l1 * w2[HL + j] + b2[j], 0.0f);
    }
    __syncthreads();

    // ---- phase 4: out[b][t] = relu(b3+b4 + hs@w3[:,t] + hl@w4[:,t]) ----
    // w3/w4 coalesced across t; hs/hl LDS broadcast (free).
    if (t < HOUT) {
        float acc = b3[t] + b4[t];
        #pragma unroll 8
        for (int i = 0; i < HG; ++i) acc += hs[i] * w3[i * HOUT + t];
        #pragma unroll 8
        for (int i = 0; i < HL; ++i) acc += hl[i] * w4[i * HOUT + t];
        out[(size_t)b * HOUT + t] = fmaxf(acc, 0.0f);
    }
}

// ---------------------------------------------------------------------------
extern "C" void kernel_launch(void* const* d_in, const int* in_sizes, int n_in,
                              void* d_out, int out_size, void* d_ws, size_t ws_size,
                              hipStream_t stream) {
    (void)d_ws; (void)ws_size; (void)in_sizes; (void)n_in; (void)out_size;
    const float* x_t = (const float*)d_in[0];
    const float* l_t = (const float*)d_in[1];
    const float* w1  = (const float*)d_in[2];
    const float* b1  = (const float*)d_in[3];
    const float* w2  = (const float*)d_in[4];
    const float* b2  = (const float*)d_in[5];
    const float* w3  = (const float*)d_in[6];
    const float* b3  = (const float*)d_in[7];
    const float* w4  = (const float*)d_in[8];
    const float* b4  = (const float*)d_in[9];

    glimpse_fused<<<B_, NT, 0, stream>>>(x_t, l_t, w1, b1, w2, b2, w3, b3, w4, b4,
                                         (float*)d_out);
}

// Round 2
// 471.671 us; speedup vs baseline: 1.1467x; 1.1467x over previous
//
#include <hip/hip_runtime.h>

// GlimpseNet on MI355X.
// Shapes: B=128, C=3, H=W=512, P=16, NP=3, HG=256, HL=128, D_IN=2304, OUT=(128,384).
// R3 structure (revert of fused R2, which lost 57us to redundant w1 reads):
//   k1 (384 blocks): one block per (b,c) stages the 64x64 patch in LDS once and
//      emits all 3 foveation levels (16^2/32^2/64^2 are concentric sub-windows).
//   k2 (288 blocks): split-K fp32 GEMM glimpse@w1, KS=18 x BK=128 -> 18 partials
//      (was 36x64: halves the partial round-trip and k3's reduction depth).
//   k3 (256 blocks): 2 blocks per batch row (uses all 256 CUs; was 128 blocks =
//      half the GPU idle). Each block: reduce partials -> hs, where-path -> hl,
//      then 192 output cols with the i-loop split 2-way across threads
//      (192 serial loads/thread instead of 384) + LDS combine.
// ws: glimpse 128*2304 f (1.18 MB) + partial 18*128*256 f (2.36 MB).

#define B_    128
#define C_    3
#define H_    512
#define W_    512
#define P_    16
#define HG    256
#define HL    128
#define DIN   2304
#define HOUT  384   // HG + HL

// gemm1 tiling
#define KS 18    // split-K chunks, 18*128 = 2304
#define BK 128
#define BM 32
#define BN 64

// ---------------------------------------------------------------------------
// k1: one block per (b,c). Stage 64x64 zero-padded patch centered at coords,
// then derive all three levels from LDS:
//   level0 = center 16x16 (rows/cols 24..39)
//   level1 = 2x2 avg-pool of center 32x32 (rows/cols 16..47)
//   level2 = 4x4 avg-pool of the full 64x64
// Sub-window equivalence with the reference holds because dynamic_slice starts
// are in [0,512] (never clamped) and zero-padding is center-consistent.
// ---------------------------------------------------------------------------
__global__ __launch_bounds__(256) void k1_foveate(
    const float* __restrict__ x, const float* __restrict__ l,
    float* __restrict__ glimpse)
{
    __shared__ float ld[64 * 64];   // 16 KiB
    const int bid = blockIdx.x;     // b*C + c
    const int b = bid / C_;
    const int c = bid % C_;
    const int t = threadIdx.x;

    // coords: trunc(0.5*((l+1)*512)) — exact pow2 scales, matches JAX bitwise.
    const float l0 = l[b * 2 + 0];
    const float l1 = l[b * 2 + 1];
    const int sx = (int)(((l0 + 1.0f) * 512.0f) * 0.5f);
    const int sy = (int)(((l1 + 1.0f) * 512.0f) * 0.5f);

    const float* xc = x + (size_t)(b * C_ + c) * (H_ * W_);

    // Stage 64x64 patch: rows sy-32..sy+31, cols sx-32..sx+31, zero-padded.
    for (int f = t; f < 64 * 64; f += 256) {
        const int r  = f >> 6;
        const int cc = f & 63;
        const int ry = sy - 32 + r;
        const int rx = sx - 32 + cc;
        ld[f] = (ry >= 0 && ry < H_ && rx >= 0 && rx < W_) ? xc[ry * W_ + rx] : 0.0f;
    }
    __syncthreads();

    const int py = t >> 4;
    const int px = t & 15;

    // level 0: direct center read
    const float v0 = ld[(24 + py) * 64 + 24 + px];

    // level 1: 2x2 pool of center 32x32
    float s1 = 0.0f;
    #pragma unroll
    for (int dy = 0; dy < 2; ++dy) {
        const float2 v = *(const float2*)&ld[(16 + 2 * py + dy) * 64 + 16 + 2 * px];
        s1 += v.x + v.y;
    }

    // level 2: 4x4 pool of full 64x64
    float s2 = 0.0f;
    #pragma unroll
    for (int dy = 0; dy < 4; ++dy) {
        const float4 v = *(const float4*)&ld[(py * 4 + dy) * 64 + px * 4];
        s2 += v.x + v.y + v.z + v.w;
    }

    float* g = glimpse + (size_t)b * DIN;
    g[(0 * C_ + c) * 256 + t] = v0;
    g[(1 * C_ + c) * 256 + t] = s1 * 0.25f;
    g[(2 * C_ + c) * 256 + t] = s2 * 0.0625f;
}

// ---------------------------------------------------------------------------
// k2: split-K GEMM  partial[ks][b][j] = glimpse[b, k0:k0+128] @ w1[k0:k0+128, j]
// grid = 16 (4 bt x 4 jt) * 18 ks = 288 blocks, 256 threads, 32x64 tile.
// LDS 49.5 KiB -> up to 3 blocks/CU.
// ---------------------------------------------------------------------------
__global__ __launch_bounds__(256) void k2_gemm1(
    const float* __restrict__ glimpse, const float* __restrict__ w1,
    float* __restrict__ partial)
{
    __shared__ float As[BM][BK + 4];   // stride 132: kills pow2 bank aliasing
    __shared__ float Bs[BK][BN];

    const int bid = blockIdx.x;
    const int ks  = bid % KS;
    const int jb  = bid / KS;
    const int jt  = jb & 3;
    const int bt  = jb >> 2;
    const int t   = threadIdx.x;
    const int k0  = ks * BK;

    // A tile: 32x128 floats = 1024 float4, 4 per thread.
    #pragma unroll
    for (int i = 0; i < 4; ++i) {
        const int f   = t + 256 * i;
        const int row = f >> 5, c4 = f & 31;
        float4 v = *(const float4*)&glimpse[(size_t)(bt * BM + row) * DIN + k0 + c4 * 4];
        *(float4*)&As[row][c4 * 4] = v;
    }
    // B tile: 128x64 floats = 2048 float4, 8 per thread.
    #pragma unroll
    for (int i = 0; i < 8; ++i) {
        const int f  = t + 256 * i;
        const int kr = f >> 4, c4 = f & 15;
        float4 v = *(const float4*)&w1[(size_t)(k0 + kr) * HG + jt * BN + c4 * 4];
        *(float4*)&Bs[kr][c4 * 4] = v;
    }
    __syncthreads();

    const int tx = t & 15;    // column group (4 cols)
    const int ty = t >> 4;    // rows ty and ty+16
    float4 acc0 = {0.f, 0.f, 0.f, 0.f};
    float4 acc1 = {0.f, 0.f, 0.f, 0.f};
    #pragma unroll 8
    for (int k = 0; k < BK; ++k) {
        const float a0 = As[ty][k];
        const float a1 = As[ty + 16][k];
        const float4 bv = *(const float4*)&Bs[k][tx * 4];
        acc0.x += a0 * bv.x; acc0.y += a0 * bv.y; acc0.z += a0 * bv.z; acc0.w += a0 * bv.w;
        acc1.x += a1 * bv.x; acc1.y += a1 * bv.y; acc1.z += a1 * bv.z; acc1.w += a1 * bv.w;
    }
    float* p0 = &partial[((size_t)(ks * B_ + bt * BM + ty)) * HG + jt * BN + tx * 4];
    *(float4*)p0 = acc0;
    float* p1 = &partial[((size_t)(ks * B_ + bt * BM + ty + 16)) * HG + jt * BN + tx * 4];
    *(float4*)p1 = acc1;
}

// ---------------------------------------------------------------------------
// k3: grid = 256 blocks (2 per batch row b; h = output-col half) x 384 threads.
//   hs = relu(b1 + sum_s partial[s][b][:])   (256 entries, LDS; duplicated per h)
//   hl = relu(l[b]@w2 + b2)                  (128 entries, LDS)
//   cols j in [h*192, h*192+192): i-loop split 2-way across threads:
//     waves 0-2: i in [0,192) of hs@w3 ; waves 3-5: i in [192,256) + hl@w4
//   LDS combine -> out.
// ---------------------------------------------------------------------------
__global__ __launch_bounds__(384) void k3_out(
    const float* __restrict__ partial, const float* __restrict__ b1,
    const float* __restrict__ w3, const float* __restrict__ b3,
    const float* __restrict__ l,  const float* __restrict__ w2,
    const float* __restrict__ b2, const float* __restrict__ w4,
    const float* __restrict__ b4, float* __restrict__ out)
{
    __shared__ float hs[HG];
    __shared__ float hl[HL];
    __shared__ float red[384];
    const int bid = blockIdx.x;
    const int b = bid >> 1;
    const int h = bid & 1;           // which 192-col half of the output
    const int t = threadIdx.x;

    if (t < HG) {
        // 18 partials with 2 independent accumulators -> pipelined loads.
        float a0 = 0.f, a1 = 0.f;
        #pragma unroll
        for (int s = 0; s < KS; s += 2) {
            a0 += partial[((size_t)((s + 0) * B_ + b)) * HG + t];
            a1 += partial[((size_t)((s + 1) * B_ + b)) * HG + t];
        }
        hs[t] = fmaxf(a0 + a1 + b1[t], 0.0f);
    } else {
        const int j = t - HG;        // 0..127
        const float l0 = l[b * 2 + 0];
        const float l1 = l[b * 2 + 1];
        hl[j] = fmaxf(l0 * w2[j] + l1 * w2[HL + j] + b2[j], 0.0f);
    }
    __syncthreads();

    // col = h*192 + (t%192); waves 0-2 take i-range A, waves 3-5 range B.
    const int col = h * 192 + (t % 192);
    float acc = 0.0f;
    if (t < 192) {
        #pragma unroll 8
        for (int i = 0; i < 192; ++i)
            acc += hs[i] * w3[i * HOUT + col];     // hs broadcast, w3 coalesced
    } else {
        #pragma unroll 8
        for (int i = 192; i < HG; ++i)
            acc += hs[i] * w3[i * HOUT + col];
        #pragma unroll 8
        for (int i = 0; i < HL; ++i)
            acc += hl[i] * w4[i * HOUT + col];
    }
    red[t] = acc;
    __syncthreads();

    if (t < 192) {
        const int c2 = h * 192 + t;
        out[(size_t)b * HOUT + c2] =
            fmaxf(red[t] + red[t + 192] + b3[c2] + b4[c2], 0.0f);
    }
}

// ---------------------------------------------------------------------------
extern "C" void kernel_launch(void* const* d_in, const int* in_sizes, int n_in,
                              void* d_out, int out_size, void* d_ws, size_t ws_size,
                              hipStream_t stream) {
    (void)in_sizes; (void)n_in; (void)out_size; (void)ws_size;
    const float* x_t = (const float*)d_in[0];
    const float* l_t = (const float*)d_in[1];
    const float* w1  = (const float*)d_in[2];
    const float* b1  = (const float*)d_in[3];
    const float* w2  = (const float*)d_in[4];
    const float* b2  = (const float*)d_in[5];
    const float* w3  = (const float*)d_in[6];
    const float* b3  = (const float*)d_in[7];
    const float* w4  = (const float*)d_in[8];
    const float* b4  = (const float*)d_in[9];
    float* out = (float*)d_out;

    float* ws      = (float*)d_ws;
    float* glimpse = ws;                               // 128*2304
    float* partial = glimpse + (size_t)B_ * DIN;       // 18*128*256

    k1_foveate<<<B_ * C_, 256, 0, stream>>>(x_t, l_t, glimpse);
    k2_gemm1<<<16 * KS, 256, 0, stream>>>(glimpse, w1, partial);
    k3_out<<<2 * B_, 384, 0, stream>>>(partial, b1, w3, b3, l_t, w2, b2, w4, b4, out);
}